// Round 4
// baseline (364.563 us; speedup 1.0000x reference)
//
#include <hip/hip_runtime.h>

// ---------------------------------------------------------------------------
// GIN 3-layer forward, bf16 pipeline:
//   CSR build (hist -> hierarchical scan -> bucket scatter)
//   per layer: H = (1+eps)*X + gather-sum  (bf16 gather, fp32 acc, 32B/lane ILP)
//              out = H @ W + b (MFMA bf16 16x16x32, 128x128 tile, global_load_lds)
//   final layer writes fp32 to d_out.
// ---------------------------------------------------------------------------

typedef __attribute__((ext_vector_type(8))) short short8;
typedef __attribute__((ext_vector_type(4))) float f32x4;

__device__ inline unsigned short f2bf(float f) {
    union { float f; unsigned u; } v; v.f = f;
    unsigned r = v.u + 0x7fffu + ((v.u >> 16) & 1u);   // RNE
    return (unsigned short)(r >> 16);
}
__device__ inline float bflo(unsigned u) { return __uint_as_float(u << 16); }
__device__ inline float bfhi(unsigned u) { return __uint_as_float(u & 0xffff0000u); }

__device__ __forceinline__ void gload_lds16(const unsigned short* g, unsigned short* l) {
    __builtin_amdgcn_global_load_lds(
        (const __attribute__((address_space(1))) unsigned int*)g,
        (__attribute__((address_space(3))) unsigned int*)l,
        16, 0, 0);
}

// ---------------- CSR build ----------------

__global__ __launch_bounds__(256) void hist_kernel(
    const int* __restrict__ dst, int* __restrict__ cnt, int nE)
{
    int e = blockIdx.x * 256 + threadIdx.x;
    if (e < nE) atomicAdd(&cnt[dst[e]], 1);
}

__global__ __launch_bounds__(1024) void scan1_kernel(
    const int* __restrict__ cnt, int* __restrict__ excl,
    int* __restrict__ bsum, int n)
{
    __shared__ int sh[1024];
    const int tid = threadIdx.x;
    const int i = blockIdx.x * 1024 + tid;
    int v = (i < n) ? cnt[i] : 0;
    sh[tid] = v;
    __syncthreads();
    #pragma unroll
    for (int off = 1; off < 1024; off <<= 1) {
        int t = (tid >= off) ? sh[tid - off] : 0;
        __syncthreads();
        sh[tid] += t;
        __syncthreads();
    }
    if (i < n) excl[i] = sh[tid] - v;
    if (tid == 1023) bsum[blockIdx.x] = sh[1023];
}

__global__ __launch_bounds__(64) void scan2_kernel(
    const int* __restrict__ bsum, int* __restrict__ boffs, int nb)
{
    __shared__ int sh[64];
    const int tid = threadIdx.x;
    int v = (tid < nb) ? bsum[tid] : 0;
    sh[tid] = v;
    __syncthreads();
    #pragma unroll
    for (int off = 1; off < 64; off <<= 1) {
        int t = (tid >= off) ? sh[tid - off] : 0;
        __syncthreads();
        sh[tid] += t;
        __syncthreads();
    }
    boffs[tid] = sh[tid] - v;  // exclusive
}

__global__ __launch_bounds__(1024) void scan3_kernel(
    const int* __restrict__ excl, const int* __restrict__ boffs,
    int* __restrict__ row_start, int* __restrict__ cursor, int n, int nE)
{
    const int i = blockIdx.x * 1024 + threadIdx.x;
    if (i < n) {
        int v = excl[i] + boffs[blockIdx.x];
        row_start[i] = v;
        cursor[i] = v;
    }
    if (i == 0) row_start[n] = nE;
}

__global__ __launch_bounds__(256) void build_adj_kernel(
    const int* __restrict__ src, const int* __restrict__ dst,
    int* __restrict__ cursor, int* __restrict__ adj, int nE)
{
    int e = blockIdx.x * 256 + threadIdx.x;
    if (e < nE) {
        int p = atomicAdd(&cursor[dst[e]], 1);
        adj[p] = src[e];
    }
}

// ---------------- dtype conversion ----------------

__global__ __launch_bounds__(256) void convert_x_kernel(
    const float* __restrict__ in, unsigned short* __restrict__ out, int n4)
{
    int i = blockIdx.x * 256 + threadIdx.x;
    if (i >= n4) return;
    float4 v = reinterpret_cast<const float4*>(in)[i];
    ushort4 o;
    o.x = f2bf(v.x); o.y = f2bf(v.y); o.z = f2bf(v.z); o.w = f2bf(v.w);
    reinterpret_cast<ushort4*>(out)[i] = o;
}

// Wt[n*K+k] = bf16(W[k*N+n])
__global__ __launch_bounds__(256) void convert_wt_kernel(
    const float* __restrict__ W, unsigned short* __restrict__ Wt,
    int kshift, int N, int total)
{
    int idx = blockIdx.x * 256 + threadIdx.x;
    if (idx >= total) return;
    int n = idx >> kshift;
    int k = idx & ((1 << kshift) - 1);
    Wt[idx] = f2bf(W[(size_t)k * N + n]);
}

// ---------------- aggregation (bf16 gather, fp32 acc, 32B/lane) ----------------

#define ACCP(v) { acc[0]+=bflo(v.x); acc[1]+=bfhi(v.x); acc[2]+=bflo(v.y); acc[3]+=bfhi(v.y); \
                  acc[4]+=bflo(v.z); acc[5]+=bfhi(v.z); acc[6]+=bflo(v.w); acc[7]+=bfhi(v.w); }
#define ACCQ(v) { acc[8]+=bflo(v.x); acc[9]+=bfhi(v.x); acc[10]+=bflo(v.y); acc[11]+=bfhi(v.y); \
                  acc[12]+=bflo(v.z); acc[13]+=bfhi(v.z); acc[14]+=bflo(v.w); acc[15]+=bfhi(v.w); }

template <int C>
__global__ __launch_bounds__(256) void aggregate_bf16(
    const unsigned short* __restrict__ X, const int* __restrict__ row_start,
    const int* __restrict__ adj, const float* __restrict__ eps_arr, int layer,
    unsigned short* __restrict__ H, int M)
{
    constexpr int U4  = C / 8;        // uint4 per row
    constexpr int TPN = C / 16;       // lanes per node, each handles 32B
    constexpr int NPB = 256 / TPN;
    const int node = blockIdx.x * NPB + (threadIdx.x / TPN);
    const int g    = threadIdx.x & (TPN - 1);
    if (node >= M) return;

    const uint4* __restrict__ X4 = reinterpret_cast<const uint4*>(X);

    float acc[16] = {};
    const int s0 = row_start[node];
    const int s1 = row_start[node + 1];

    int j = s0;
    for (; j + 3 < s1; j += 4) {
        const int a0 = adj[j], a1 = adj[j+1], a2 = adj[j+2], a3 = adj[j+3];
        const uint4 p0 = X4[(size_t)a0 * U4 + g];
        const uint4 q0 = X4[(size_t)a0 * U4 + TPN + g];
        const uint4 p1 = X4[(size_t)a1 * U4 + g];
        const uint4 q1 = X4[(size_t)a1 * U4 + TPN + g];
        const uint4 p2 = X4[(size_t)a2 * U4 + g];
        const uint4 q2 = X4[(size_t)a2 * U4 + TPN + g];
        const uint4 p3 = X4[(size_t)a3 * U4 + g];
        const uint4 q3 = X4[(size_t)a3 * U4 + TPN + g];
        ACCP(p0); ACCQ(q0); ACCP(p1); ACCQ(q1);
        ACCP(p2); ACCQ(q2); ACCP(p3); ACCQ(q3);
    }
    for (; j < s1; ++j) {
        const int a = adj[j];
        const uint4 p = X4[(size_t)a * U4 + g];
        const uint4 q = X4[(size_t)a * U4 + TPN + g];
        ACCP(p); ACCQ(q);
    }

    const float epsv = 1.0f + eps_arr[layer];
    const uint4 xp = X4[(size_t)node * U4 + g];
    const uint4 xq = X4[(size_t)node * U4 + TPN + g];
    float o[16];
    o[0]  = epsv * bflo(xp.x) + acc[0];  o[1]  = epsv * bfhi(xp.x) + acc[1];
    o[2]  = epsv * bflo(xp.y) + acc[2];  o[3]  = epsv * bfhi(xp.y) + acc[3];
    o[4]  = epsv * bflo(xp.z) + acc[4];  o[5]  = epsv * bfhi(xp.z) + acc[5];
    o[6]  = epsv * bflo(xp.w) + acc[6];  o[7]  = epsv * bfhi(xp.w) + acc[7];
    o[8]  = epsv * bflo(xq.x) + acc[8];  o[9]  = epsv * bfhi(xq.x) + acc[9];
    o[10] = epsv * bflo(xq.y) + acc[10]; o[11] = epsv * bfhi(xq.y) + acc[11];
    o[12] = epsv * bflo(xq.z) + acc[12]; o[13] = epsv * bfhi(xq.z) + acc[13];
    o[14] = epsv * bflo(xq.w) + acc[14]; o[15] = epsv * bfhi(xq.w) + acc[15];

    uint4 ov0, ov1;
    ov0.x = (unsigned)f2bf(o[0])  | ((unsigned)f2bf(o[1])  << 16);
    ov0.y = (unsigned)f2bf(o[2])  | ((unsigned)f2bf(o[3])  << 16);
    ov0.z = (unsigned)f2bf(o[4])  | ((unsigned)f2bf(o[5])  << 16);
    ov0.w = (unsigned)f2bf(o[6])  | ((unsigned)f2bf(o[7])  << 16);
    ov1.x = (unsigned)f2bf(o[8])  | ((unsigned)f2bf(o[9])  << 16);
    ov1.y = (unsigned)f2bf(o[10]) | ((unsigned)f2bf(o[11]) << 16);
    ov1.z = (unsigned)f2bf(o[12]) | ((unsigned)f2bf(o[13]) << 16);
    ov1.w = (unsigned)f2bf(o[14]) | ((unsigned)f2bf(o[15]) << 16);
    uint4* H4 = reinterpret_cast<uint4*>(H);
    H4[(size_t)node * U4 + g]       = ov0;
    H4[(size_t)node * U4 + TPN + g] = ov1;
}

// ---------------- MFMA GEMM (m97 structure): out = A @ Wt^T + b ----------------
// 128x128 tile, BK=32, 256 threads = 4 waves (2x2), wave = 64x64 (4x4 frags).
// A is [Mpad][K] bf16 (Mpad multiple of 128), Wt is [N][K] bf16.

#define TM 128
#define TN 128
#define TK 32

template <int RELU, int BF16OUT>
__global__ __launch_bounds__(256) void gemm_mfma(
    const unsigned short* __restrict__ A, const unsigned short* __restrict__ Wt,
    const float* __restrict__ bias, void* __restrict__ out,
    int M, int K, int N)
{
    __shared__ __align__(16) unsigned short As[TM * TK];
    __shared__ __align__(16) unsigned short Bs[TN * TK];

    const int t    = threadIdx.x;
    const int bm   = blockIdx.y * TM;
    const int bn   = blockIdx.x * TN;
    const int w    = t >> 6, lane = t & 63;
    const int wr   = w >> 1, wc = w & 1;
    const int lr   = lane & 15, ko = lane >> 4;

    // staging: wave w covers rows [w*32, w*32+32); per issue 16 rows.
    // lane l -> row +(l>>2), col (l&3)*8 shorts (16B). LDS linear = lane*16B.
    const int srow = lane >> 2;
    const int scol = (lane & 3) * 8;
    const unsigned short* aG0 = A  + (size_t)(bm + w*32 + srow) * K + scol;
    const unsigned short* aG1 = aG0 + (size_t)16 * K;
    const unsigned short* bG0 = Wt + (size_t)(bn + w*32 + srow) * K + scol;
    const unsigned short* bG1 = bG0 + (size_t)16 * K;
    unsigned short* lA0 = &As[(w*32)      * TK];
    unsigned short* lA1 = &As[(w*32 + 16) * TK];
    unsigned short* lB0 = &Bs[(w*32)      * TK];
    unsigned short* lB1 = &Bs[(w*32 + 16) * TK];

    f32x4 acc[4][4] = {};

    for (int k0 = 0; k0 < K; k0 += TK) {
        gload_lds16(aG0 + k0, lA0);
        gload_lds16(aG1 + k0, lA1);
        gload_lds16(bG0 + k0, lB0);
        gload_lds16(bG1 + k0, lB1);
        __syncthreads();

        short8 af[4], bf8[4];
        #pragma unroll
        for (int fm = 0; fm < 4; ++fm)
            af[fm] = *reinterpret_cast<const short8*>(&As[(wr*64 + fm*16 + lr) * TK + ko*8]);
        #pragma unroll
        for (int fn = 0; fn < 4; ++fn)
            bf8[fn] = *reinterpret_cast<const short8*>(&Bs[(wc*64 + fn*16 + lr) * TK + ko*8]);
        #pragma unroll
        for (int fm = 0; fm < 4; ++fm)
            #pragma unroll
            for (int fn = 0; fn < 4; ++fn)
                acc[fm][fn] = __builtin_amdgcn_mfma_f32_16x16x32_bf16(
                    af[fm], bf8[fn], acc[fm][fn], 0, 0, 0);

        __syncthreads();
    }

    // epilogue: C/D layout col = lane&15, row = (lane>>4)*4 + r
    #pragma unroll
    for (int fn = 0; fn < 4; ++fn) {
        const int col = bn + wc*64 + fn*16 + lr;
        const float bb = bias[col];
        #pragma unroll
        for (int fm = 0; fm < 4; ++fm) {
            const int rbase = bm + wr*64 + fm*16 + ko*4;
            #pragma unroll
            for (int r = 0; r < 4; ++r) {
                const int row = rbase + r;
                if (row < M) {
                    float v = acc[fm][fn][r] + bb;
                    if (RELU) v = fmaxf(v, 0.f);
                    if (BF16OUT)
                        ((unsigned short*)out)[(size_t)row * N + col] = f2bf(v);
                    else
                        ((float*)out)[(size_t)row * N + col] = v;
                }
            }
        }
    }
}

// ---------------- launch ----------------

extern "C" void kernel_launch(void* const* d_in, const int* in_sizes, int n_in,
                              void* d_out, int out_size, void* d_ws, size_t ws_size,
                              hipStream_t stream)
{
    const float* x   = (const float*)d_in[0];
    const int*   ei  = (const int*)  d_in[1];
    const float* W1  = (const float*)d_in[2];
    const float* b1  = (const float*)d_in[3];
    const float* W2  = (const float*)d_in[4];
    const float* b2  = (const float*)d_in[5];
    const float* W3  = (const float*)d_in[6];
    const float* b3  = (const float*)d_in[7];
    const float* eps = (const float*)d_in[8];

    const int M  = in_sizes[0] / 128;   // 50000
    const int nE = in_sizes[1] / 2;     // 800000
    const int Mp = ((M + TM - 1) / TM) * TM;  // padded rows for GEMM A reads
    const int* srcI = ei;
    const int* dstI = ei + nE;

    // workspace layout
    char* p = (char*)d_ws;
    unsigned short* xb   = (unsigned short*)p; p += (size_t)M  * 128 * 2;
    unsigned short* A1   = (unsigned short*)p; p += (size_t)Mp * 128 * 2;  // GEMM-read: padded
    unsigned short* bufA = (unsigned short*)p; p += (size_t)Mp * 256 * 2;
    unsigned short* bufB = (unsigned short*)p; p += (size_t)Mp * 256 * 2;  // GEMM-read: padded
    unsigned short* Wt1  = (unsigned short*)p; p += (size_t)128 * 256 * 2;
    unsigned short* Wt2  = (unsigned short*)p; p += (size_t)256 * 256 * 2;
    unsigned short* Wt3  = (unsigned short*)p; p += (size_t)256 * 256 * 2;
    int* cnt       = (int*)p; p += (size_t)M * 4;
    int* excl      = (int*)p; p += (size_t)M * 4;
    int* bsum      = (int*)p; p += 64 * 4;
    int* boffs     = (int*)p; p += 64 * 4;
    int* row_start = (int*)p; p += (size_t)(M + 2) * 4;
    int* cursor    = (int*)p; p += (size_t)M * 4;
    int* adj       = (int*)p; p += (size_t)nE * 4;

    const int nbl = (M + 1023) / 1024;   // 49

    // CSR build
    hipMemsetAsync(cnt, 0, (size_t)M * sizeof(int), stream);
    hist_kernel<<<(nE + 255) / 256, 256, 0, stream>>>(dstI, cnt, nE);
    scan1_kernel<<<nbl, 1024, 0, stream>>>(cnt, excl, bsum, M);
    scan2_kernel<<<1, 64, 0, stream>>>(bsum, boffs, nbl);
    scan3_kernel<<<nbl, 1024, 0, stream>>>(excl, boffs, row_start, cursor, M, nE);
    build_adj_kernel<<<(nE + 255) / 256, 256, 0, stream>>>(srcI, dstI, cursor, adj, nE);

    // conversions
    convert_x_kernel<<<(M * 128 / 4 + 255) / 256, 256, 0, stream>>>(x, xb, M * 128 / 4);
    convert_wt_kernel<<<(128 * 256 + 255) / 256, 256, 0, stream>>>(W1, Wt1, 7, 256, 128 * 256);
    convert_wt_kernel<<<(256 * 256 + 255) / 256, 256, 0, stream>>>(W2, Wt2, 8, 256, 256 * 256);
    convert_wt_kernel<<<(256 * 256 + 255) / 256, 256, 0, stream>>>(W3, Wt3, 8, 256, 256 * 256);

    const dim3 ggrid(256 / TN, Mp / TM);   // (2, 391)

    // layer 1 (K=128)
    aggregate_bf16<128><<<(M + 31) / 32, 256, 0, stream>>>(xb, row_start, adj, eps, 0, A1, M);
    gemm_mfma<1, 1><<<ggrid, 256, 0, stream>>>(A1, Wt1, b1, bufA, M, 128, 256);

    // layer 2 (K=256)
    aggregate_bf16<256><<<(M + 15) / 16, 256, 0, stream>>>(bufA, row_start, adj, eps, 1, bufB, M);
    gemm_mfma<1, 1><<<ggrid, 256, 0, stream>>>(bufB, Wt2, b2, bufA, M, 256, 256);

    // layer 3 (K=256, no relu, fp32 out)
    aggregate_bf16<256><<<(M + 15) / 16, 256, 0, stream>>>(bufA, row_start, adj, eps, 2, bufB, M);
    gemm_mfma<0, 0><<<ggrid, 256, 0, stream>>>(bufB, Wt3, b3, d_out, M, 256, 256);
}

// Round 5
// 351.857 us; speedup vs baseline: 1.0361x; 1.0361x over previous
//
#include <hip/hip_runtime.h>

// ---------------------------------------------------------------------------
// GIN 3-layer forward, bf16 pipeline:
//   CSR build (hist -> hierarchical scan -> bucket scatter)
//   per layer: H = (1+eps)*X + gather-sum  (bf16 gather 16B/lane, fp32 acc)
//              out = H @ W + b (MFMA bf16 16x16x32, 64x256 full-N tile,
//                              global_load_lds staging)
//   final layer writes fp32 to d_out.
// ---------------------------------------------------------------------------

typedef __attribute__((ext_vector_type(8))) short short8;
typedef __attribute__((ext_vector_type(4))) float f32x4;

__device__ inline unsigned short f2bf(float f) {
    union { float f; unsigned u; } v; v.f = f;
    unsigned r = v.u + 0x7fffu + ((v.u >> 16) & 1u);   // RNE
    return (unsigned short)(r >> 16);
}
__device__ inline float bflo(unsigned u) { return __uint_as_float(u << 16); }
__device__ inline float bfhi(unsigned u) { return __uint_as_float(u & 0xffff0000u); }

__device__ __forceinline__ void gload_lds16(const unsigned short* g, unsigned short* l) {
    __builtin_amdgcn_global_load_lds(
        (const __attribute__((address_space(1))) unsigned int*)g,
        (__attribute__((address_space(3))) unsigned int*)l,
        16, 0, 0);
}

// ---------------- CSR build ----------------

__global__ __launch_bounds__(256) void hist_kernel(
    const int* __restrict__ dst, int* __restrict__ cnt, int nE)
{
    int e = blockIdx.x * 256 + threadIdx.x;
    if (e < nE) atomicAdd(&cnt[dst[e]], 1);
}

__global__ __launch_bounds__(1024) void scan1_kernel(
    const int* __restrict__ cnt, int* __restrict__ excl,
    int* __restrict__ bsum, int n)
{
    __shared__ int sh[1024];
    const int tid = threadIdx.x;
    const int i = blockIdx.x * 1024 + tid;
    int v = (i < n) ? cnt[i] : 0;
    sh[tid] = v;
    __syncthreads();
    #pragma unroll
    for (int off = 1; off < 1024; off <<= 1) {
        int t = (tid >= off) ? sh[tid - off] : 0;
        __syncthreads();
        sh[tid] += t;
        __syncthreads();
    }
    if (i < n) excl[i] = sh[tid] - v;
    if (tid == 1023) bsum[blockIdx.x] = sh[1023];
}

__global__ __launch_bounds__(64) void scan2_kernel(
    const int* __restrict__ bsum, int* __restrict__ boffs, int nb)
{
    __shared__ int sh[64];
    const int tid = threadIdx.x;
    int v = (tid < nb) ? bsum[tid] : 0;
    sh[tid] = v;
    __syncthreads();
    #pragma unroll
    for (int off = 1; off < 64; off <<= 1) {
        int t = (tid >= off) ? sh[tid - off] : 0;
        __syncthreads();
        sh[tid] += t;
        __syncthreads();
    }
    boffs[tid] = sh[tid] - v;  // exclusive
}

__global__ __launch_bounds__(1024) void scan3_kernel(
    const int* __restrict__ excl, const int* __restrict__ boffs,
    int* __restrict__ row_start, int* __restrict__ cursor, int n, int nE)
{
    const int i = blockIdx.x * 1024 + threadIdx.x;
    if (i < n) {
        int v = excl[i] + boffs[blockIdx.x];
        row_start[i] = v;
        cursor[i] = v;
    }
    if (i == 0) row_start[n] = nE;
}

__global__ __launch_bounds__(256) void build_adj_kernel(
    const int* __restrict__ src, const int* __restrict__ dst,
    int* __restrict__ cursor, int* __restrict__ adj, int nE)
{
    int e = blockIdx.x * 256 + threadIdx.x;
    if (e < nE) {
        int p = atomicAdd(&cursor[dst[e]], 1);
        adj[p] = src[e];
    }
}

// ---------------- dtype conversion ----------------

__global__ __launch_bounds__(256) void convert_x_kernel(
    const float* __restrict__ in, unsigned short* __restrict__ out, int n4)
{
    int i = blockIdx.x * 256 + threadIdx.x;
    if (i >= n4) return;
    float4 v = reinterpret_cast<const float4*>(in)[i];
    ushort4 o;
    o.x = f2bf(v.x); o.y = f2bf(v.y); o.z = f2bf(v.z); o.w = f2bf(v.w);
    reinterpret_cast<ushort4*>(out)[i] = o;
}

// All three weights, transposed+converted in one launch.
// Wt[n*K+k] = bf16(W[k*256+n]); sizes: W1 128x256, W2/W3 256x256.
__global__ __launch_bounds__(256) void convert_w_all(
    const float* __restrict__ W1, const float* __restrict__ W2,
    const float* __restrict__ W3, unsigned short* __restrict__ Wt1,
    unsigned short* __restrict__ Wt2, unsigned short* __restrict__ Wt3)
{
    int idx = blockIdx.x * 256 + threadIdx.x;
    if (idx < 32768) {                       // W1: K=128
        int n = idx >> 7, k = idx & 127;
        Wt1[idx] = f2bf(W1[(size_t)k * 256 + n]);
    } else if (idx < 32768 + 65536) {        // W2: K=256
        int i = idx - 32768;
        int n = i >> 8, k = i & 255;
        Wt2[i] = f2bf(W2[(size_t)k * 256 + n]);
    } else {                                 // W3: K=256
        int i = idx - 32768 - 65536;
        int n = i >> 8, k = i & 255;
        Wt3[i] = f2bf(W3[(size_t)k * 256 + n]);
    }
}

// ---------------- aggregation (bf16 gather, fp32 acc, 16B/lane) ----------------

#define ACC8(v) { acc[0]+=bflo(v.x); acc[1]+=bfhi(v.x); acc[2]+=bflo(v.y); acc[3]+=bfhi(v.y); \
                  acc[4]+=bflo(v.z); acc[5]+=bfhi(v.z); acc[6]+=bflo(v.w); acc[7]+=bfhi(v.w); }

template <int C>
__global__ __launch_bounds__(256) void aggregate_bf16(
    const unsigned short* __restrict__ X, const int* __restrict__ row_start,
    const int* __restrict__ adj, const float* __restrict__ eps_arr, int layer,
    unsigned short* __restrict__ H, int M)
{
    constexpr int TPN = C / 8;        // lanes per node (16B = 8 bf16 each)
    constexpr int NPB = 256 / TPN;
    const int node = blockIdx.x * NPB + (threadIdx.x / TPN);
    const int c8   = threadIdx.x & (TPN - 1);
    if (node >= M) return;

    const uint4* __restrict__ X4 = reinterpret_cast<const uint4*>(X);

    float acc[8] = {0.f,0.f,0.f,0.f,0.f,0.f,0.f,0.f};
    const int s0 = row_start[node];
    const int s1 = row_start[node + 1];

    int j = s0;
    for (; j + 3 < s1; j += 4) {
        int a0 = adj[j], a1 = adj[j+1], a2 = adj[j+2], a3 = adj[j+3];
        uint4 v0 = X4[(size_t)a0 * TPN + c8];
        uint4 v1 = X4[(size_t)a1 * TPN + c8];
        uint4 v2 = X4[(size_t)a2 * TPN + c8];
        uint4 v3 = X4[(size_t)a3 * TPN + c8];
        ACC8(v0); ACC8(v1); ACC8(v2); ACC8(v3);
    }
    for (; j < s1; ++j) {
        uint4 v = X4[(size_t)adj[j] * TPN + c8];
        ACC8(v);
    }

    const uint4 xv = X4[(size_t)node * TPN + c8];
    const float epsv = 1.0f + eps_arr[layer];
    float o[8];
    o[0] = epsv * bflo(xv.x) + acc[0]; o[1] = epsv * bfhi(xv.x) + acc[1];
    o[2] = epsv * bflo(xv.y) + acc[2]; o[3] = epsv * bfhi(xv.y) + acc[3];
    o[4] = epsv * bflo(xv.z) + acc[4]; o[5] = epsv * bfhi(xv.z) + acc[5];
    o[6] = epsv * bflo(xv.w) + acc[6]; o[7] = epsv * bfhi(xv.w) + acc[7];

    uint4 ov;
    ov.x = (unsigned)f2bf(o[0]) | ((unsigned)f2bf(o[1]) << 16);
    ov.y = (unsigned)f2bf(o[2]) | ((unsigned)f2bf(o[3]) << 16);
    ov.z = (unsigned)f2bf(o[4]) | ((unsigned)f2bf(o[5]) << 16);
    ov.w = (unsigned)f2bf(o[6]) | ((unsigned)f2bf(o[7]) << 16);
    reinterpret_cast<uint4*>(H)[(size_t)node * TPN + c8] = ov;
}

// ---------------- MFMA GEMM: out[M,256] = A[Mp,K] @ Wt[256,K]^T + b ----------
// 64x256 tile (full N), BK=32, 256 threads = 4 waves side by side along N.
// Each wave: 64 rows x 64 cols = 4x4 16x16 frags = 16 MFMA / K-step.
// A read ONCE per row (full-N tile). Staging via global_load_lds width=16.

#define TM 64
#define TN 256
#define TK 32

template <int RELU, int BF16OUT>
__global__ __launch_bounds__(256) void gemm_mfma(
    const unsigned short* __restrict__ A, const unsigned short* __restrict__ Wt,
    const float* __restrict__ bias, void* __restrict__ out,
    int M, int K)
{
    __shared__ __align__(16) unsigned short As[TM * TK];   //  4 KB
    __shared__ __align__(16) unsigned short Bs[TN * TK];   // 16 KB

    const int t    = threadIdx.x;
    const int bm   = blockIdx.x * TM;
    const int w    = t >> 6, lane = t & 63;
    const int lr   = lane & 15, ko = lane >> 4;

    // staging: lane l covers row (l>>2), col (l&3)*8 within a 16-row stripe.
    const int srow = lane >> 2;          // 0..15
    const int scol = (lane & 3) * 8;     // 0,8,16,24 shorts
    // A: wave w stages rows [w*16, w*16+16)
    const unsigned short* aG = A + (size_t)(bm + w*16 + srow) * K + scol;
    unsigned short* lA = &As[(w*16 + srow) * TK + scol];
    // B: wave w stages rows [w*64, w*64+64) in 4 issues of 16 rows
    const unsigned short* bG = Wt + (size_t)(w*64 + srow) * K + scol;
    unsigned short* lB = &Bs[(w*64 + srow) * TK + scol];

    f32x4 acc[4][4] = {};

    for (int k0 = 0; k0 < K; k0 += TK) {
        gload_lds16(aG + k0, lA);
        #pragma unroll
        for (int i = 0; i < 4; ++i)
            gload_lds16(bG + (size_t)(i*16) * K + k0, lB + (i*16) * TK);
        __syncthreads();

        short8 af[4], bf8[4];
        #pragma unroll
        for (int fm = 0; fm < 4; ++fm)
            af[fm] = *reinterpret_cast<const short8*>(&As[(fm*16 + lr) * TK + ko*8]);
        #pragma unroll
        for (int fn = 0; fn < 4; ++fn)
            bf8[fn] = *reinterpret_cast<const short8*>(&Bs[(w*64 + fn*16 + lr) * TK + ko*8]);
        #pragma unroll
        for (int fm = 0; fm < 4; ++fm)
            #pragma unroll
            for (int fn = 0; fn < 4; ++fn)
                acc[fm][fn] = __builtin_amdgcn_mfma_f32_16x16x32_bf16(
                    af[fm], bf8[fn], acc[fm][fn], 0, 0, 0);

        __syncthreads();
    }

    // epilogue: C/D layout col = lane&15, row = (lane>>4)*4 + r
    #pragma unroll
    for (int fn = 0; fn < 4; ++fn) {
        const int col = w*64 + fn*16 + lr;
        const float bb = bias[col];
        #pragma unroll
        for (int fm = 0; fm < 4; ++fm) {
            const int rbase = bm + fm*16 + ko*4;
            #pragma unroll
            for (int r = 0; r < 4; ++r) {
                const int row = rbase + r;
                if (row < M) {
                    float v = acc[fm][fn][r] + bb;
                    if (RELU) v = fmaxf(v, 0.f);
                    if (BF16OUT)
                        ((unsigned short*)out)[(size_t)row * TN + col] = f2bf(v);
                    else
                        ((float*)out)[(size_t)row * TN + col] = v;
                }
            }
        }
    }
}

// ---------------- launch ----------------

extern "C" void kernel_launch(void* const* d_in, const int* in_sizes, int n_in,
                              void* d_out, int out_size, void* d_ws, size_t ws_size,
                              hipStream_t stream)
{
    const float* x   = (const float*)d_in[0];
    const int*   ei  = (const int*)  d_in[1];
    const float* W1  = (const float*)d_in[2];
    const float* b1  = (const float*)d_in[3];
    const float* W2  = (const float*)d_in[4];
    const float* b2  = (const float*)d_in[5];
    const float* W3  = (const float*)d_in[6];
    const float* b3  = (const float*)d_in[7];
    const float* eps = (const float*)d_in[8];

    const int M  = in_sizes[0] / 128;   // 50000
    const int nE = in_sizes[1] / 2;     // 800000
    const int Mp = ((M + 127) / 128) * 128;   // padded rows for GEMM A reads
    const int* srcI = ei;
    const int* dstI = ei + nE;

    // workspace layout
    char* p = (char*)d_ws;
    unsigned short* xb   = (unsigned short*)p; p += (size_t)M  * 128 * 2;
    unsigned short* A1   = (unsigned short*)p; p += (size_t)Mp * 128 * 2;
    unsigned short* bufA = (unsigned short*)p; p += (size_t)Mp * 256 * 2;
    unsigned short* bufB = (unsigned short*)p; p += (size_t)Mp * 256 * 2;
    unsigned short* Wt1  = (unsigned short*)p; p += (size_t)128 * 256 * 2;
    unsigned short* Wt2  = (unsigned short*)p; p += (size_t)256 * 256 * 2;
    unsigned short* Wt3  = (unsigned short*)p; p += (size_t)256 * 256 * 2;
    int* cnt       = (int*)p; p += (size_t)M * 4;
    int* excl      = (int*)p; p += (size_t)M * 4;
    int* bsum      = (int*)p; p += 64 * 4;
    int* boffs     = (int*)p; p += 64 * 4;
    int* row_start = (int*)p; p += (size_t)(M + 2) * 4;
    int* cursor    = (int*)p; p += (size_t)M * 4;
    int* adj       = (int*)p; p += (size_t)nE * 4;

    const int nbl = (M + 1023) / 1024;   // 49

    // CSR build
    hipMemsetAsync(cnt, 0, (size_t)M * sizeof(int), stream);
    hist_kernel<<<(nE + 255) / 256, 256, 0, stream>>>(dstI, cnt, nE);
    scan1_kernel<<<nbl, 1024, 0, stream>>>(cnt, excl, bsum, M);
    scan2_kernel<<<1, 64, 0, stream>>>(bsum, boffs, nbl);
    scan3_kernel<<<nbl, 1024, 0, stream>>>(excl, boffs, row_start, cursor, M, nE);
    build_adj_kernel<<<(nE + 255) / 256, 256, 0, stream>>>(srcI, dstI, cursor, adj, nE);

    // conversions
    convert_x_kernel<<<(M * 128 / 4 + 255) / 256, 256, 0, stream>>>(x, xb, M * 128 / 4);
    convert_w_all<<<(32768 + 65536 + 65536) / 256, 256, 0, stream>>>(
        W1, W2, W3, Wt1, Wt2, Wt3);

    const int ggrid = Mp / TM;   // 784 blocks

    // layer 1 (K=128)
    aggregate_bf16<128><<<(M + 15) / 16, 256, 0, stream>>>(xb, row_start, adj, eps, 0, A1, M);
    gemm_mfma<1, 1><<<ggrid, 256, 0, stream>>>(A1, Wt1, b1, bufA, M, 128);

    // layer 2 (K=256)
    aggregate_bf16<256><<<(M + 7) / 8, 256, 0, stream>>>(bufA, row_start, adj, eps, 1, bufB, M);
    gemm_mfma<1, 1><<<ggrid, 256, 0, stream>>>(bufB, Wt2, b2, bufA, M, 256);

    // layer 3 (K=256, no relu, fp32 out)
    aggregate_bf16<256><<<(M + 7) / 8, 256, 0, stream>>>(bufA, row_start, adj, eps, 2, bufB, M);
    gemm_mfma<0, 0><<<ggrid, 256, 0, stream>>>(bufB, Wt3, b3, d_out, M, 256);
}

// Round 6
// 322.521 us; speedup vs baseline: 1.1304x; 1.0910x over previous
//
#include <hip/hip_runtime.h>

// ---------------------------------------------------------------------------
// GIN 3-layer forward, fused bf16 pipeline:
//   prep:   convert x->bf16, hist(dst), convert W1..3 -> k-subtiled bf16
//   CSR:    scan -> bucket scatter
//   layer:  ONE kernel: block = 32 node rows.
//           phase A: H[32][CIN] = (1+eps)x + gather-sum  -> LDS (subtiled)
//           phase B: out[32][256] = H @ W + b (MFMA 16x16x32, B staged via
//                    global_load_lds from k-subtiled Wsub, conflict-free)
//   final layer writes fp32 to d_out.
// ---------------------------------------------------------------------------

typedef __attribute__((ext_vector_type(8))) short short8;
typedef __attribute__((ext_vector_type(4))) float f32x4;

__device__ inline unsigned short f2bf(float f) {
    union { float f; unsigned u; } v; v.f = f;
    unsigned r = v.u + 0x7fffu + ((v.u >> 16) & 1u);   // RNE
    return (unsigned short)(r >> 16);
}
__device__ inline float bflo(unsigned u) { return __uint_as_float(u << 16); }
__device__ inline float bfhi(unsigned u) { return __uint_as_float(u & 0xffff0000u); }

__device__ __forceinline__ void gload_lds16(const unsigned short* g, unsigned short* l) {
    __builtin_amdgcn_global_load_lds(
        (const __attribute__((address_space(1))) unsigned int*)g,
        (__attribute__((address_space(3))) unsigned int*)l,
        16, 0, 0);
}

#define ACC8(v) { acc[0]+=bflo(v.x); acc[1]+=bfhi(v.x); acc[2]+=bflo(v.y); acc[3]+=bfhi(v.y); \
                  acc[4]+=bflo(v.z); acc[5]+=bfhi(v.z); acc[6]+=bflo(v.w); acc[7]+=bfhi(v.w); }

// ---------------- prep: x->bf16, hist, W->subtiled bf16 ----------------
// item ranges: [0, M*16)           : convert 8 floats of x
//              [M*16, M*16+nE)     : hist atomic
//              [.., +163840)       : W1 (32768) | W2 (65536) | W3 (65536)
__global__ __launch_bounds__(256) void prep_kernel(
    const float* __restrict__ x, const int* __restrict__ dst,
    const float* __restrict__ W1, const float* __restrict__ W2,
    const float* __restrict__ W3,
    unsigned short* __restrict__ xb, int* __restrict__ cnt,
    unsigned short* __restrict__ Ws1, unsigned short* __restrict__ Ws2,
    unsigned short* __restrict__ Ws3, int M, int nE)
{
    const int i  = blockIdx.x * 256 + threadIdx.x;
    const int nx = M * 16;
    if (i < nx) {
        const float4* xf = reinterpret_cast<const float4*>(x);
        float4 a = xf[2*i], b = xf[2*i + 1];
        uint4 o;
        o.x = (unsigned)f2bf(a.x) | ((unsigned)f2bf(a.y) << 16);
        o.y = (unsigned)f2bf(a.z) | ((unsigned)f2bf(a.w) << 16);
        o.z = (unsigned)f2bf(b.x) | ((unsigned)f2bf(b.y) << 16);
        o.w = (unsigned)f2bf(b.z) | ((unsigned)f2bf(b.w) << 16);
        reinterpret_cast<uint4*>(xb)[i] = o;
    } else if (i < nx + nE) {
        atomicAdd(&cnt[dst[i - nx]], 1);
    } else {
        int j = i - nx - nE;
        const float* W; unsigned short* D;
        if (j < 32768)       { W = W1; D = Ws1; }
        else if (j < 98304)  { W = W2; D = Ws2; j -= 32768; }
        else if (j < 163840) { W = W3; D = Ws3; j -= 98304; }
        else return;
        const int k = j >> 8, n = j & 255;
        // Wsub[k/8][n][k%8] = bf16(W[k][n])
        D[((size_t)(k >> 3) * 256 + n) * 8 + (k & 7)] = f2bf(W[(size_t)k * 256 + n]);
    }
}

// ---------------- CSR scan + scatter ----------------

__global__ __launch_bounds__(1024) void scan1_kernel(
    const int* __restrict__ cnt, int* __restrict__ excl,
    int* __restrict__ bsum, int n)
{
    __shared__ int sh[1024];
    const int tid = threadIdx.x;
    const int i = blockIdx.x * 1024 + tid;
    int v = (i < n) ? cnt[i] : 0;
    sh[tid] = v;
    __syncthreads();
    #pragma unroll
    for (int off = 1; off < 1024; off <<= 1) {
        int t = (tid >= off) ? sh[tid - off] : 0;
        __syncthreads();
        sh[tid] += t;
        __syncthreads();
    }
    if (i < n) excl[i] = sh[tid] - v;
    if (tid == 1023) bsum[blockIdx.x] = sh[1023];
}

__global__ __launch_bounds__(64) void scan2_kernel(
    const int* __restrict__ bsum, int* __restrict__ boffs, int nb)
{
    __shared__ int sh[64];
    const int tid = threadIdx.x;
    int v = (tid < nb) ? bsum[tid] : 0;
    sh[tid] = v;
    __syncthreads();
    #pragma unroll
    for (int off = 1; off < 64; off <<= 1) {
        int t = (tid >= off) ? sh[tid - off] : 0;
        __syncthreads();
        sh[tid] += t;
        __syncthreads();
    }
    boffs[tid] = sh[tid] - v;  // exclusive
}

__global__ __launch_bounds__(1024) void scan3_kernel(
    const int* __restrict__ excl, const int* __restrict__ boffs,
    int* __restrict__ row_start, int* __restrict__ cursor, int n, int nE)
{
    const int i = blockIdx.x * 1024 + threadIdx.x;
    if (i < n) {
        int v = excl[i] + boffs[blockIdx.x];
        row_start[i] = v;
        cursor[i] = v;
    }
    if (i == 0) row_start[n] = nE;
}

__global__ __launch_bounds__(256) void build_adj_kernel(
    const int* __restrict__ src, const int* __restrict__ dst,
    int* __restrict__ cursor, int* __restrict__ adj, int nE)
{
    int e = blockIdx.x * 256 + threadIdx.x;
    if (e < nE) {
        int p = atomicAdd(&cursor[dst[e]], 1);
        adj[p] = src[e];
    }
}

// ---------------- fused layer: aggregate 32 rows + GEMM(32x256) ------------
// Hs: k-subtiled A tile  [CIN/8][32][8]  (kb, row, k%8)
// Bs: k-subtiled B step  [4][256][8]     (kb-within-step, n, k%8)
// frag reads: 16 lanes hit 16 consecutive 16B slots -> conflict-free.

template <int CIN, int RELU, int BF16OUT>
__global__ __launch_bounds__(256) void fused_layer(
    const unsigned short* __restrict__ X,
    const int* __restrict__ row_start, const int* __restrict__ adj,
    const unsigned short* __restrict__ Wsub,
    const float* __restrict__ bias, const float* __restrict__ eps_arr,
    int layer, void* __restrict__ out, int M)
{
    constexpr int KB     = CIN / 8;    // kblocks in A
    constexpr int S      = CIN / 32;   // K-steps
    constexpr int TPN    = CIN / 8;    // lanes per node in agg
    constexpr int NPB    = 256 / TPN;  // nodes per agg pass
    constexpr int PASSES = 32 / NPB;

    __shared__ __align__(16) unsigned short Hs[KB][32][8];
    __shared__ __align__(16) unsigned short Bs[4][256][8];

    const int t    = threadIdx.x;
    const int bm   = blockIdx.x * 32;
    const int w    = t >> 6, lane = t & 63;
    const int lr   = lane & 15, ko = lane >> 4;
    unsigned short* BsLin = &Bs[0][0][0];

    // prefetch B for step 0 (hides under aggregation)
    #pragma unroll
    for (int i = 0; i < 4; ++i)
        gload_lds16(Wsub + i*2048 + t*8, BsLin + i*2048 + t*8);

    // ---- phase A: aggregate 32 rows into Hs ----
    const uint4* __restrict__ X4 = reinterpret_cast<const uint4*>(X);
    const int c8 = t & (TPN - 1);
    const int rb = t / TPN;
    #pragma unroll
    for (int p = 0; p < PASSES; ++p) {
        const int r = p * NPB + rb;
        const int node = bm + r;
        uint4 ov = {0, 0, 0, 0};
        if (node < M) {
            float acc[8] = {};
            const int s0 = row_start[node], s1 = row_start[node + 1];
            int j = s0;
            for (; j + 3 < s1; j += 4) {
                const int a0 = adj[j], a1 = adj[j+1], a2 = adj[j+2], a3 = adj[j+3];
                const uint4 v0 = X4[(size_t)a0 * TPN + c8];
                const uint4 v1 = X4[(size_t)a1 * TPN + c8];
                const uint4 v2 = X4[(size_t)a2 * TPN + c8];
                const uint4 v3 = X4[(size_t)a3 * TPN + c8];
                ACC8(v0); ACC8(v1); ACC8(v2); ACC8(v3);
            }
            for (; j < s1; ++j) {
                const uint4 v = X4[(size_t)adj[j] * TPN + c8];
                ACC8(v);
            }
            const uint4 xv = X4[(size_t)node * TPN + c8];
            const float epsv = 1.0f + eps_arr[layer];
            float o[8];
            o[0] = epsv * bflo(xv.x) + acc[0]; o[1] = epsv * bfhi(xv.x) + acc[1];
            o[2] = epsv * bflo(xv.y) + acc[2]; o[3] = epsv * bfhi(xv.y) + acc[3];
            o[4] = epsv * bflo(xv.z) + acc[4]; o[5] = epsv * bfhi(xv.z) + acc[5];
            o[6] = epsv * bflo(xv.w) + acc[6]; o[7] = epsv * bfhi(xv.w) + acc[7];
            ov.x = (unsigned)f2bf(o[0]) | ((unsigned)f2bf(o[1]) << 16);
            ov.y = (unsigned)f2bf(o[2]) | ((unsigned)f2bf(o[3]) << 16);
            ov.z = (unsigned)f2bf(o[4]) | ((unsigned)f2bf(o[5]) << 16);
            ov.w = (unsigned)f2bf(o[6]) | ((unsigned)f2bf(o[7]) << 16);
        }
        *reinterpret_cast<uint4*>(&Hs[c8][r][0]) = ov;   // c8 == kblock index
    }

    // ---- phase B: GEMM ----
    f32x4 acc[2][4] = {};
    for (int s = 0;;) {
        __syncthreads();   // Hs (first iter) + Bs(s) ready
        short8 af[2], bf8[4];
        #pragma unroll
        for (int fm = 0; fm < 2; ++fm)
            af[fm] = *reinterpret_cast<const short8*>(&Hs[s*4 + ko][fm*16 + lr][0]);
        #pragma unroll
        for (int fn = 0; fn < 4; ++fn)
            bf8[fn] = *reinterpret_cast<const short8*>(&Bs[ko][w*64 + fn*16 + lr][0]);
        #pragma unroll
        for (int fm = 0; fm < 2; ++fm)
            #pragma unroll
            for (int fn = 0; fn < 4; ++fn)
                acc[fm][fn] = __builtin_amdgcn_mfma_f32_16x16x32_bf16(
                    af[fm], bf8[fn], acc[fm][fn], 0, 0, 0);
        if (++s == S) break;
        __syncthreads();   // all waves done reading Bs(s-1)
        const unsigned short* g = Wsub + (size_t)s * 8192;
        #pragma unroll
        for (int i = 0; i < 4; ++i)
            gload_lds16(g + i*2048 + t*8, BsLin + i*2048 + t*8);
    }

    // ---- epilogue: C/D layout col = lane&15, row = (lane>>4)*4 + r ----
    #pragma unroll
    for (int fn = 0; fn < 4; ++fn) {
        const int col = w*64 + fn*16 + lr;
        const float bb = bias[col];
        #pragma unroll
        for (int fm = 0; fm < 2; ++fm) {
            const int rbase = bm + fm*16 + ko*4;
            #pragma unroll
            for (int r = 0; r < 4; ++r) {
                const int row = rbase + r;
                if (row < M) {
                    float v = acc[fm][fn][r] + bb;
                    if (RELU) v = fmaxf(v, 0.f);
                    if (BF16OUT)
                        ((unsigned short*)out)[(size_t)row * 256 + col] = f2bf(v);
                    else
                        ((float*)out)[(size_t)row * 256 + col] = v;
                }
            }
        }
    }
}

// ---------------- launch ----------------

extern "C" void kernel_launch(void* const* d_in, const int* in_sizes, int n_in,
                              void* d_out, int out_size, void* d_ws, size_t ws_size,
                              hipStream_t stream)
{
    const float* x   = (const float*)d_in[0];
    const int*   ei  = (const int*)  d_in[1];
    const float* W1  = (const float*)d_in[2];
    const float* b1  = (const float*)d_in[3];
    const float* W2  = (const float*)d_in[4];
    const float* b2  = (const float*)d_in[5];
    const float* W3  = (const float*)d_in[6];
    const float* b3  = (const float*)d_in[7];
    const float* eps = (const float*)d_in[8];

    const int M  = in_sizes[0] / 128;   // 50000
    const int nE = in_sizes[1] / 2;     // 800000
    const int Mp = ((M + 127) / 128) * 128;   // buffer row padding
    const int* srcI = ei;
    const int* dstI = ei + nE;

    // workspace layout
    char* p = (char*)d_ws;
    unsigned short* xb  = (unsigned short*)p; p += (size_t)M  * 128 * 2;
    unsigned short* h1  = (unsigned short*)p; p += (size_t)Mp * 256 * 2;
    unsigned short* h2  = (unsigned short*)p; p += (size_t)Mp * 256 * 2;
    unsigned short* Ws1 = (unsigned short*)p; p += (size_t)128 * 256 * 2;
    unsigned short* Ws2 = (unsigned short*)p; p += (size_t)256 * 256 * 2;
    unsigned short* Ws3 = (unsigned short*)p; p += (size_t)256 * 256 * 2;
    int* cnt       = (int*)p; p += (size_t)M * 4;
    int* excl      = (int*)p; p += (size_t)M * 4;
    int* bsum      = (int*)p; p += 64 * 4;
    int* boffs     = (int*)p; p += 64 * 4;
    int* row_start = (int*)p; p += (size_t)(M + 2) * 4;
    int* cursor    = (int*)p; p += (size_t)M * 4;
    int* adj       = (int*)p; p += (size_t)nE * 4;

    const int nbl = (M + 1023) / 1024;   // 49

    // prep (+hist) and CSR build
    hipMemsetAsync(cnt, 0, (size_t)M * sizeof(int), stream);
    {
        const int total = M * 16 + nE + 163840;
        prep_kernel<<<(total + 255) / 256, 256, 0, stream>>>(
            x, dstI, W1, W2, W3, xb, cnt, Ws1, Ws2, Ws3, M, nE);
    }
    scan1_kernel<<<nbl, 1024, 0, stream>>>(cnt, excl, bsum, M);
    scan2_kernel<<<1, 64, 0, stream>>>(bsum, boffs, nbl);
    scan3_kernel<<<nbl, 1024, 0, stream>>>(excl, boffs, row_start, cursor, M, nE);
    build_adj_kernel<<<(nE + 255) / 256, 256, 0, stream>>>(srcI, dstI, cursor, adj, nE);

    const int nblk = (M + 31) / 32;   // 1563

    fused_layer<128, 1, 1><<<nblk, 256, 0, stream>>>(
        xb, row_start, adj, Ws1, b1, eps, 0, h1, M);
    fused_layer<256, 1, 1><<<nblk, 256, 0, stream>>>(
        h1, row_start, adj, Ws2, b2, eps, 1, h2, M);
    fused_layer<256, 0, 0><<<nblk, 256, 0, stream>>>(
        h2, row_start, adj, Ws3, b3, eps, 2, d_out, M);
}